// Round 1
// baseline (35535.254 us; speedup 1.0000x reference)
//
#include <hip/hip_runtime.h>
#include <hip/hip_bf16.h>

#define T_STEPS 512
#define BATCH   64
#define NIN     512
#define HID     512
#define G4      2048      // 4*HID
#define TBROWS  32768     // T_STEPS*BATCH

typedef __attribute__((ext_vector_type(4))) float f32x4;
typedef __attribute__((ext_vector_type(8))) short bf16x8_t;

static __device__ __forceinline__ unsigned short f2bf_bits(float x){
  unsigned int u = __float_as_uint(x);
  unsigned int r = (u + 0x7FFFu + ((u >> 16) & 1u)) >> 16;   // RNE
  return (unsigned short)r;
}
static __device__ __forceinline__ float bf_bits2f(unsigned short u){
  return __uint_as_float(((unsigned int)u) << 16);
}

// ---------------------------------------------------------------- split f32 -> bf16 hi/lo
__global__ __launch_bounds__(256) void k_split(const float* __restrict__ src,
                                               unsigned short* __restrict__ hi,
                                               unsigned short* __restrict__ lo,
                                               long n4){
  long i = (long)blockIdx.x * blockDim.x + threadIdx.x;
  long stride = (long)gridDim.x * blockDim.x;
  for (; i < n4; i += stride){
    float4 v = reinterpret_cast<const float4*>(src)[i];
    ushort4 h, l;
    h.x = f2bf_bits(v.x); l.x = f2bf_bits(v.x - bf_bits2f(h.x));
    h.y = f2bf_bits(v.y); l.y = f2bf_bits(v.y - bf_bits2f(h.y));
    h.z = f2bf_bits(v.z); l.z = f2bf_bits(v.z - bf_bits2f(h.z));
    h.w = f2bf_bits(v.w); l.w = f2bf_bits(v.w - bf_bits2f(h.w));
    reinterpret_cast<ushort4*>(hi)[i] = h;
    reinterpret_cast<ushort4*>(lo)[i] = l;
  }
}

// ---------------------------------------------------------------- bf16x3 GEMM, C[g][n] = A[g][:]·B[n][:] + bias
// A: [2048][K] bf16 hi/lo (W_ih of one dir); B: [*][K] bf16 hi/lo (x or layer-0 out, K-contiguous)
// grid: (16, Nslab/128, 2 dirs); 128x128 tile, BK=32, 4 waves (2x2 quadrants of 64x64)
__global__ __launch_bounds__(256) void k_gemm_x3(
    const unsigned short* __restrict__ Ah0, const unsigned short* __restrict__ Al0,
    const unsigned short* __restrict__ Ah1, const unsigned short* __restrict__ Al1,
    const unsigned short* __restrict__ Bh,  const unsigned short* __restrict__ Bl,
    float* __restrict__ C0, float* __restrict__ C1,
    const float* __restrict__ bih0, const float* __restrict__ bhh0,
    const float* __restrict__ bih1, const float* __restrict__ bhh1,
    int K, int Nslab, int noff0, int noff1)
{
  const int z = blockIdx.z;
  const unsigned short* Ah = z ? Ah1 : Ah0;
  const unsigned short* Al = z ? Al1 : Al0;
  float* Cc            = z ? C1  : C0;
  const float* bih     = z ? bih1 : bih0;
  const float* bhh     = z ? bhh1 : bhh0;
  const int noff       = z ? noff1 : noff0;

  const int m0 = blockIdx.x * 128;
  const int n0 = blockIdx.y * 128;

  __shared__ __align__(16) unsigned short sAh[128*32];
  __shared__ __align__(16) unsigned short sAl[128*32];
  __shared__ __align__(16) unsigned short sBh[128*32];
  __shared__ __align__(16) unsigned short sBl[128*32];

  const int tid  = threadIdx.x;
  const int wave = tid >> 6, lane = tid & 63;
  const int wm = wave >> 1, wn = wave & 1;

  f32x4 acc[4][4];
  #pragma unroll
  for (int a = 0; a < 4; a++)
    #pragma unroll
    for (int b = 0; b < 4; b++) acc[a][b] = (f32x4)0.f;

  // each wave stages one 128x32 tile (8 KB) per k-step
  unsigned short* sTile =
      (wave == 0) ? sAh : (wave == 1) ? sAl : (wave == 2) ? sBh : sBl;
  const unsigned short* gBase =
      (wave == 0) ? (Ah + (long)m0 * K) :
      (wave == 1) ? (Al + (long)m0 * K) :
      (wave == 2) ? (Bh + (long)(noff + n0) * K) :
                    (Bl + (long)(noff + n0) * K);

  for (int k0 = 0; k0 < K; k0 += 32){
    #pragma unroll
    for (int i = 0; i < 8; i++){
      int row = i * 16 + (lane >> 2);
      const unsigned short* g = gBase + (long)row * K + k0 + (lane & 3) * 8;
      unsigned short* l = sTile + i * 512;   // 1 KiB per instr, lane*16B auto
      __builtin_amdgcn_global_load_lds((const __attribute__((address_space(1))) void*)g,
                                       (__attribute__((address_space(3))) void*)l,
                                       16, 0, 0);
    }
    __syncthreads();

    const int fr = lane & 15, fk = (lane >> 4) * 8;
    bf16x8_t ah[4], al[4], bh[4], bl[4];
    #pragma unroll
    for (int mi = 0; mi < 4; mi++){
      int r = wm * 64 + mi * 16 + fr;
      ah[mi] = *reinterpret_cast<const bf16x8_t*>(&sAh[r * 32 + fk]);
      al[mi] = *reinterpret_cast<const bf16x8_t*>(&sAl[r * 32 + fk]);
    }
    #pragma unroll
    for (int ni = 0; ni < 4; ni++){
      int r = wn * 64 + ni * 16 + fr;
      bh[ni] = *reinterpret_cast<const bf16x8_t*>(&sBh[r * 32 + fk]);
      bl[ni] = *reinterpret_cast<const bf16x8_t*>(&sBl[r * 32 + fk]);
    }
    #pragma unroll
    for (int mi = 0; mi < 4; mi++)
      #pragma unroll
      for (int ni = 0; ni < 4; ni++){
        acc[mi][ni] = __builtin_amdgcn_mfma_f32_16x16x32_bf16(ah[mi], bh[ni], acc[mi][ni], 0, 0, 0);
        acc[mi][ni] = __builtin_amdgcn_mfma_f32_16x16x32_bf16(ah[mi], bl[ni], acc[mi][ni], 0, 0, 0);
        acc[mi][ni] = __builtin_amdgcn_mfma_f32_16x16x32_bf16(al[mi], bh[ni], acc[mi][ni], 0, 0, 0);
      }
    __syncthreads();
  }

  const int fr = lane & 15, fg = lane >> 4;
  #pragma unroll
  for (int mi = 0; mi < 4; mi++){
    #pragma unroll
    for (int r = 0; r < 4; r++){
      int g = m0 + wm * 64 + mi * 16 + fg * 4 + r;
      float bsum = bih[g] + bhh[g];
      #pragma unroll
      for (int ni = 0; ni < 4; ni++){
        int n = n0 + wn * 64 + ni * 16 + fr;
        Cc[(long)g * Nslab + n] = acc[mi][ni][r] + bsum;
      }
    }
  }
}

// ---------------------------------------------------------------- one LSTM timestep, both dirs
// grid 256 blocks: bid>>7 = dir, (bid&127)*4 = j0. thread: b = tid&63, q = tid>>6, j = j0+q.
__global__ __launch_bounds__(256) void k_step(
    const float* __restrict__ Whh0, const float* __restrict__ Whh1,
    const float* __restrict__ slabF, const float* __restrict__ slabB,
    const float* __restrict__ h_in, float* __restrict__ h_out,
    float* __restrict__ cst, const float* __restrict__ mask,
    float* __restrict__ outT,
    unsigned short* __restrict__ oHi, unsigned short* __restrict__ oLo,
    float* __restrict__ outF,
    int t0, int t1, int sl0, int sl1, int Nslab)
{
  const int bid = blockIdx.x;
  const int d   = bid >> 7;
  const int j0  = (bid & 127) * 4;
  const int tid = threadIdx.x;
  const int b   = tid & 63;
  const int q   = tid >> 6;
  const int j   = j0 + q;

  const float* Whh  = d ? Whh1 : Whh0;
  const float* slab = d ? slabB : slabF;
  const int t  = d ? t1 : t0;
  const int sl = d ? sl1 : sl0;

  __shared__ __align__(16) float Wl[4 * 512 * 4];   // [q][k][gate-type], 32 KiB

  {
    const int jrow = j0 + q;
    #pragma unroll
    for (int i = 0; i < 8; i++){
      int k = (tid & 63) + i * 64;
      float w0 = Whh[(0 * 512 + jrow) * 512 + k];
      float w1 = Whh[(1 * 512 + jrow) * 512 + k];
      float w2 = Whh[(2 * 512 + jrow) * 512 + k];
      float w3 = Whh[(3 * 512 + jrow) * 512 + k];
      f32x4 wv = {w0, w1, w2, w3};
      *reinterpret_cast<f32x4*>(&Wl[(q * 512 + k) * 4]) = wv;
    }
  }
  __syncthreads();

  const float* hrow = h_in + d * (512 * 64) + b;
  float a0 = 0.f, a1 = 0.f, a2 = 0.f, a3 = 0.f;
  #pragma unroll 4
  for (int k = 0; k < 512; k++){
    float hv = hrow[k * 64];
    f32x4 w = *reinterpret_cast<const f32x4*>(&Wl[(q * 512 + k) * 4]);
    a0 += hv * w[0]; a1 += hv * w[1]; a2 += hv * w[2]; a3 += hv * w[3];
  }

  const int n = sl * 64 + b;
  float gi = slab[(long)(0 * 512 + j) * Nslab + n] + a0;
  float gf = slab[(long)(1 * 512 + j) * Nslab + n] + a1;
  float gg = slab[(long)(2 * 512 + j) * Nslab + n] + a2;
  float go = slab[(long)(3 * 512 + j) * Nslab + n] + a3;

  float i_ = 1.f / (1.f + __expf(-gi));
  float f_ = 1.f / (1.f + __expf(-gf));
  float g_ = tanhf(gg);
  float o_ = 1.f / (1.f + __expf(-go));

  const int cidx = (d * 512 + j) * 64 + b;
  float cn = f_ * cst[cidx] + i_ * g_;
  float hn = o_ * tanhf(cn);
  float m  = mask[t * 64 + b];
  hn *= m; cn *= m;
  cst[cidx] = cn;
  h_out[d * (512 * 64) + j * 64 + b] = hn;

  if (outT){
    outT[(long)(d * 512 + j) * TBROWS + t * 64 + b] = hn;       // coalesced
  } else if (oHi){
    long o = (long)(t * 64 + b) * 1024 + d * 512 + j;
    unsigned short hb = f2bf_bits(hn);
    oHi[o] = hb;
    oLo[o] = f2bf_bits(hn - bf_bits2f(hb));
  } else {
    outF[(long)(t * 64 + b) * 1024 + d * 512 + j] = hn;
  }
}

// ---------------------------------------------------------------- transposes [1024][TBROWS] -> [TBROWS][1024]
__global__ __launch_bounds__(256) void k_transpose_split(const float* __restrict__ src,
                                                         unsigned short* __restrict__ hi,
                                                         unsigned short* __restrict__ lo){
  __shared__ float tile[64][65];
  const int g0 = blockIdx.x * 64, n0 = blockIdx.y * 64;
  const int lane = threadIdx.x & 63, rg = threadIdx.x >> 6;
  #pragma unroll
  for (int i = 0; i < 16; i++){
    int row = rg * 16 + i;
    tile[row][lane] = src[(long)(g0 + row) * TBROWS + n0 + lane];
  }
  __syncthreads();
  #pragma unroll
  for (int i = 0; i < 16; i++){
    int row = rg * 16 + i;
    float v = tile[lane][row];
    long o = (long)(n0 + row) * 1024 + g0 + lane;
    unsigned short hb = f2bf_bits(v);
    hi[o] = hb;
    lo[o] = f2bf_bits(v - bf_bits2f(hb));
  }
}

__global__ __launch_bounds__(256) void k_transpose_out(const float* __restrict__ src,
                                                       float* __restrict__ dst){
  __shared__ float tile[64][65];
  const int g0 = blockIdx.x * 64, n0 = blockIdx.y * 64;
  const int lane = threadIdx.x & 63, rg = threadIdx.x >> 6;
  #pragma unroll
  for (int i = 0; i < 16; i++){
    int row = rg * 16 + i;
    tile[row][lane] = src[(long)(g0 + row) * TBROWS + n0 + lane];
  }
  __syncthreads();
  #pragma unroll
  for (int i = 0; i < 16; i++){
    int row = rg * 16 + i;
    dst[(long)(n0 + row) * 1024 + g0 + lane] = tile[lane][row];
  }
}

// ---------------------------------------------------------------- host
extern "C" void kernel_launch(void* const* d_in, const int* in_sizes, int n_in,
                              void* d_out, int out_size, void* d_ws, size_t ws_size,
                              hipStream_t stream)
{
  (void)in_sizes; (void)n_in; (void)out_size;
  const float* x    = (const float*)d_in[0];
  const float* mask = (const float*)d_in[1];
  const float* wih[2][2] = {{(const float*)d_in[2],  (const float*)d_in[6]},
                            {(const float*)d_in[10], (const float*)d_in[14]}};
  const float* whh[2][2] = {{(const float*)d_in[3],  (const float*)d_in[7]},
                            {(const float*)d_in[11], (const float*)d_in[15]}};
  const float* bih[2][2] = {{(const float*)d_in[4],  (const float*)d_in[8]},
                            {(const float*)d_in[12], (const float*)d_in[16]}};
  const float* bhh[2][2] = {{(const float*)d_in[5],  (const float*)d_in[9]},
                            {(const float*)d_in[13], (const float*)d_in[17]}};

  char* wsb = (char*)d_ws;
  size_t off = 0;
  auto alloc = [&](size_t bytes)->char*{
    char* p = wsb + off; off += (bytes + 255) & ~(size_t)255; return p;
  };

  unsigned short* xhi  = (unsigned short*)alloc((size_t)TBROWS * NIN * 2);
  unsigned short* xlo  = (unsigned short*)alloc((size_t)TBROWS * NIN * 2);
  unsigned short* o0hi = (unsigned short*)alloc((size_t)TBROWS * 1024 * 2);
  unsigned short* o0lo = (unsigned short*)alloc((size_t)TBROWS * 1024 * 2);

  unsigned short* wsp[2][2][2];  // [layer][dir][hi/lo]
  for (int l = 0; l < 2; l++){
    size_t nel = (size_t)G4 * (l ? 1024 : 512);
    for (int dd = 0; dd < 2; dd++){
      wsp[l][dd][0] = (unsigned short*)alloc(nel * 2);
      wsp[l][dd][1] = (unsigned short*)alloc(nel * 2);
    }
  }
  float* hbuf = (float*)alloc((size_t)2 * 2 * 512 * 64 * 4);
  float* cbuf = (float*)alloc((size_t)2 * 512 * 64 * 4);

  size_t fixed = off;
  size_t tbuf_bytes = (size_t)1024 * TBROWS * 4;
  auto slab_b = [](int C){ return ((size_t)G4 * C * 64 * 4 + 255) & ~(size_t)255; };

  int C = 64, use_tbuf = 1;
  while (C > 8 && fixed + tbuf_bytes + 256 + 2 * slab_b(C) > ws_size) C >>= 1;
  if (fixed + tbuf_bytes + 256 + 2 * slab_b(C) > ws_size){
    use_tbuf = 0; C = 64;
    while (C > 8 && fixed + 2 * slab_b(C) > ws_size) C >>= 1;
  }

  float* tbuf = use_tbuf ? (float*)alloc(tbuf_bytes) : nullptr;
  float* slabF = (float*)alloc(slab_b(C));
  float* slabB = (float*)alloc(slab_b(C));
  const int Nslab = C * 64;
  const int phases = T_STEPS / C;

  // ---- prepasses: bf16 hi/lo splits
  k_split<<<2048, 256, 0, stream>>>(x, xhi, xlo, (long)TBROWS * NIN / 4);
  for (int l = 0; l < 2; l++){
    long n4 = (long)G4 * (l ? 1024 : 512) / 4;
    for (int dd = 0; dd < 2; dd++)
      k_split<<<1024, 256, 0, stream>>>(wih[l][dd], wsp[l][dd][0], wsp[l][dd][1], n4);
  }

  for (int layer = 0; layer < 2; layer++){
    const unsigned short* Bh = layer ? o0hi : xhi;
    const unsigned short* Bl = layer ? o0lo : xlo;
    const int K = layer ? 1024 : 512;

    hipMemsetAsync(hbuf, 0, (size_t)2 * 2 * 512 * 64 * 4, stream);
    hipMemsetAsync(cbuf, 0, (size_t)2 * 512 * 64 * 4, stream);

    for (int p = 0; p < phases; p++){
      const int tf0 = p * C;
      const int tb0 = T_STEPS - (p + 1) * C;
      dim3 gg(16, Nslab / 128, 2);
      k_gemm_x3<<<gg, 256, 0, stream>>>(
          wsp[layer][0][0], wsp[layer][0][1], wsp[layer][1][0], wsp[layer][1][1],
          Bh, Bl, slabF, slabB,
          bih[layer][0], bhh[layer][0], bih[layer][1], bhh[layer][1],
          K, Nslab, tf0 * 64, tb0 * 64);

      for (int s = p * C; s < (p + 1) * C; s++){
        float* hin  = hbuf + (size_t)(s & 1) * (2 * 512 * 64);
        float* hout = hbuf + (size_t)((s + 1) & 1) * (2 * 512 * 64);
        const int sl = s - p * C;
        float* oT = use_tbuf ? tbuf : nullptr;
        unsigned short* dh = (!use_tbuf && layer == 0) ? o0hi : nullptr;
        unsigned short* dl = (!use_tbuf && layer == 0) ? o0lo : nullptr;
        float* dfo = (!use_tbuf && layer == 1) ? (float*)d_out : nullptr;
        k_step<<<256, 256, 0, stream>>>(
            whh[layer][0], whh[layer][1], slabF, slabB,
            hin, hout, cbuf, mask, oT, dh, dl, dfo,
            s, T_STEPS - 1 - s, sl, C - 1 - sl, Nslab);
      }
    }

    if (use_tbuf){
      dim3 tg(16, 512);
      if (layer == 0) k_transpose_split<<<tg, 256, 0, stream>>>(tbuf, o0hi, o0lo);
      else            k_transpose_out  <<<tg, 256, 0, stream>>>(tbuf, (float*)d_out);
    }
  }
}

// Round 2
// 10435.407 us; speedup vs baseline: 3.4053x; 3.4053x over previous
//
#include <hip/hip_runtime.h>
#include <hip/hip_bf16.h>

#define T_STEPS 512
#define BATCH   64
#define NIN     512
#define HID     512
#define G4      2048      // 4*HID
#define TBROWS  32768     // T_STEPS*BATCH

typedef __attribute__((ext_vector_type(4))) float f32x4;
typedef __attribute__((ext_vector_type(8))) short bf16x8_t;

static __device__ __forceinline__ unsigned short f2bf_bits(float x){
  unsigned int u = __float_as_uint(x);
  unsigned int r = (u + 0x7FFFu + ((u >> 16) & 1u)) >> 16;   // RNE
  return (unsigned short)r;
}
static __device__ __forceinline__ float bf_bits2f(unsigned short u){
  return __uint_as_float(((unsigned int)u) << 16);
}

// ---------------------------------------------------------------- split f32 -> bf16 hi/lo
__global__ __launch_bounds__(256) void k_split(const float* __restrict__ src,
                                               unsigned short* __restrict__ hi,
                                               unsigned short* __restrict__ lo,
                                               long n4){
  long i = (long)blockIdx.x * blockDim.x + threadIdx.x;
  long stride = (long)gridDim.x * blockDim.x;
  for (; i < n4; i += stride){
    float4 v = reinterpret_cast<const float4*>(src)[i];
    ushort4 h, l;
    h.x = f2bf_bits(v.x); l.x = f2bf_bits(v.x - bf_bits2f(h.x));
    h.y = f2bf_bits(v.y); l.y = f2bf_bits(v.y - bf_bits2f(h.y));
    h.z = f2bf_bits(v.z); l.z = f2bf_bits(v.z - bf_bits2f(h.z));
    h.w = f2bf_bits(v.w); l.w = f2bf_bits(v.w - bf_bits2f(h.w));
    reinterpret_cast<ushort4*>(hi)[i] = h;
    reinterpret_cast<ushort4*>(lo)[i] = l;
  }
}

// ---------------------------------------------------------------- pack Whh[2048][512] -> W4[u][k] = {Wi,Wf,Wg,Wo}
__global__ __launch_bounds__(256) void k_pack_w(const float* __restrict__ Whh,
                                                float4* __restrict__ W4){
  int idx = blockIdx.x * 256 + threadIdx.x;   // 262144 total
  int u = idx >> 9, k = idx & 511;
  float4 v;
  v.x = Whh[(0 * 512 + u) * 512 + k];
  v.y = Whh[(1 * 512 + u) * 512 + k];
  v.z = Whh[(2 * 512 + u) * 512 + k];
  v.w = Whh[(3 * 512 + u) * 512 + k];
  W4[idx] = v;
}

// ---------------------------------------------------------------- bf16x3 GEMM (unchanged from R1)
__global__ __launch_bounds__(256) void k_gemm_x3(
    const unsigned short* __restrict__ Ah0, const unsigned short* __restrict__ Al0,
    const unsigned short* __restrict__ Ah1, const unsigned short* __restrict__ Al1,
    const unsigned short* __restrict__ Bh,  const unsigned short* __restrict__ Bl,
    float* __restrict__ C0, float* __restrict__ C1,
    const float* __restrict__ bih0, const float* __restrict__ bhh0,
    const float* __restrict__ bih1, const float* __restrict__ bhh1,
    int K, int Nslab, int noff0, int noff1)
{
  const int z = blockIdx.z;
  const unsigned short* Ah = z ? Ah1 : Ah0;
  const unsigned short* Al = z ? Al1 : Al0;
  float* Cc            = z ? C1  : C0;
  const float* bih     = z ? bih1 : bih0;
  const float* bhh     = z ? bhh1 : bhh0;
  const int noff       = z ? noff1 : noff0;

  const int m0 = blockIdx.x * 128;
  const int n0 = blockIdx.y * 128;

  __shared__ __align__(16) unsigned short sAh[128*32];
  __shared__ __align__(16) unsigned short sAl[128*32];
  __shared__ __align__(16) unsigned short sBh[128*32];
  __shared__ __align__(16) unsigned short sBl[128*32];

  const int tid  = threadIdx.x;
  const int wave = tid >> 6, lane = tid & 63;
  const int wm = wave >> 1, wn = wave & 1;

  f32x4 acc[4][4];
  #pragma unroll
  for (int a = 0; a < 4; a++)
    #pragma unroll
    for (int b = 0; b < 4; b++) acc[a][b] = (f32x4)0.f;

  unsigned short* sTile =
      (wave == 0) ? sAh : (wave == 1) ? sAl : (wave == 2) ? sBh : sBl;
  const unsigned short* gBase =
      (wave == 0) ? (Ah + (long)m0 * K) :
      (wave == 1) ? (Al + (long)m0 * K) :
      (wave == 2) ? (Bh + (long)(noff + n0) * K) :
                    (Bl + (long)(noff + n0) * K);

  for (int k0 = 0; k0 < K; k0 += 32){
    #pragma unroll
    for (int i = 0; i < 8; i++){
      int row = i * 16 + (lane >> 2);
      const unsigned short* g = gBase + (long)row * K + k0 + (lane & 3) * 8;
      unsigned short* l = sTile + i * 512;
      __builtin_amdgcn_global_load_lds((const __attribute__((address_space(1))) void*)g,
                                       (__attribute__((address_space(3))) void*)l,
                                       16, 0, 0);
    }
    __syncthreads();

    const int fr = lane & 15, fk = (lane >> 4) * 8;
    bf16x8_t ah[4], al[4], bh[4], bl[4];
    #pragma unroll
    for (int mi = 0; mi < 4; mi++){
      int r = wm * 64 + mi * 16 + fr;
      ah[mi] = *reinterpret_cast<const bf16x8_t*>(&sAh[r * 32 + fk]);
      al[mi] = *reinterpret_cast<const bf16x8_t*>(&sAl[r * 32 + fk]);
    }
    #pragma unroll
    for (int ni = 0; ni < 4; ni++){
      int r = wn * 64 + ni * 16 + fr;
      bh[ni] = *reinterpret_cast<const bf16x8_t*>(&sBh[r * 32 + fk]);
      bl[ni] = *reinterpret_cast<const bf16x8_t*>(&sBl[r * 32 + fk]);
    }
    #pragma unroll
    for (int mi = 0; mi < 4; mi++)
      #pragma unroll
      for (int ni = 0; ni < 4; ni++){
        acc[mi][ni] = __builtin_amdgcn_mfma_f32_16x16x32_bf16(ah[mi], bh[ni], acc[mi][ni], 0, 0, 0);
        acc[mi][ni] = __builtin_amdgcn_mfma_f32_16x16x32_bf16(ah[mi], bl[ni], acc[mi][ni], 0, 0, 0);
        acc[mi][ni] = __builtin_amdgcn_mfma_f32_16x16x32_bf16(al[mi], bh[ni], acc[mi][ni], 0, 0, 0);
      }
    __syncthreads();
  }

  const int fr = lane & 15, fg = lane >> 4;
  #pragma unroll
  for (int mi = 0; mi < 4; mi++){
    #pragma unroll
    for (int r = 0; r < 4; r++){
      int g = m0 + wm * 64 + mi * 16 + fg * 4 + r;
      float bsum = bih[g] + bhh[g];
      #pragma unroll
      for (int ni = 0; ni < 4; ni++){
        int n = n0 + wn * 64 + ni * 16 + fr;
        Cc[(long)g * Nslab + n] = acc[mi][ni][r] + bsum;
      }
    }
  }
}

// ---------------------------------------------------------------- one LSTM timestep, both dirs (v2)
// 256 blocks x 512 threads. bid>>7 = dir; (bid&127)*4 = u-quad.
// wave w: u = uq + (w&3), k-half = w>>2. lane = batch.
// W4: [512 u][512 k] float4 {i,f,g,o} — wave-uniform loads (L2-resident).
// h4_in/out: [dir][128 kb][64 b] float4 (4 consecutive k per float4).
__global__ __launch_bounds__(512) void k_step2(
    const float4* __restrict__ W4F, const float4* __restrict__ W4B,
    const float* __restrict__ slabF, const float* __restrict__ slabB,
    const float4* __restrict__ h4_in, float4* __restrict__ h4_out,
    float* __restrict__ cst, const float* __restrict__ mask,
    float* __restrict__ outT,
    unsigned short* __restrict__ oHi, unsigned short* __restrict__ oLo,
    float* __restrict__ outF,
    int t0, int t1, int sl0, int sl1, int Nslab)
{
  __shared__ __align__(16) float4 hS[8192];     // 128 KiB: [128 kb][64 b]
  __shared__ __align__(16) float4 red[4][64];   // 4 KiB: upper-half partials

  const int bid = blockIdx.x;
  const int d   = bid >> 7;
  const int uq  = (bid & 127) * 4;
  const int tid = threadIdx.x;
  const int w   = tid >> 6;
  const int b   = tid & 63;

  const float4* W4  = d ? W4B : W4F;
  const float* slab = d ? slabB : slabF;
  const int t  = d ? t1 : t0;
  const int sl = d ? sl1 : sl0;

  // stage this dir's h into LDS (128 KiB, 16 x 8KiB async rounds)
  {
    const float4* src = h4_in + (size_t)d * 8192;
    #pragma unroll
    for (int r = 0; r < 16; r++){
      __builtin_amdgcn_global_load_lds(
          (const __attribute__((address_space(1))) void*)(src + r * 512 + tid),
          (__attribute__((address_space(3))) void*)(hS + r * 512 + tid), 16, 0, 0);
    }
  }
  __syncthreads();

  const int u  = uq + (w & 3);
  const int kh = w >> 2;
  const int su  = __builtin_amdgcn_readfirstlane(u);
  const int skh = __builtin_amdgcn_readfirstlane(kh);

  const float4* Wp = W4 + ((size_t)su * 512 + (size_t)skh * 256);  // this wave's 256-k slice
  const float4* hp = hS + skh * 4096 + b;                          // [kb][b]

  f32x4 acc = {0.f, 0.f, 0.f, 0.f};
  #pragma unroll 4
  for (int kb = 0; kb < 64; kb++){
    float4 h4 = hp[kb * 64];
    float4 w0 = Wp[kb * 4 + 0];
    float4 w1 = Wp[kb * 4 + 1];
    float4 w2 = Wp[kb * 4 + 2];
    float4 w3 = Wp[kb * 4 + 3];
    acc.x += w0.x * h4.x; acc.y += w0.y * h4.x; acc.z += w0.z * h4.x; acc.w += w0.w * h4.x;
    acc.x += w1.x * h4.y; acc.y += w1.y * h4.y; acc.z += w1.z * h4.y; acc.w += w1.w * h4.y;
    acc.x += w2.x * h4.z; acc.y += w2.y * h4.z; acc.z += w2.z * h4.z; acc.w += w2.w * h4.z;
    acc.x += w3.x * h4.w; acc.y += w3.y * h4.w; acc.z += w3.z * h4.w; acc.w += w3.w * h4.w;
  }

  if (w >= 4){
    float4 st; st.x = acc.x; st.y = acc.y; st.z = acc.z; st.w = acc.w;
    red[w - 4][b] = st;
  }
  __syncthreads();

  if (w < 4){
    float4 r2 = red[w][b];
    const int n = sl * 64 + b;
    float gi = slab[(size_t)(0 * 512 + u) * Nslab + n] + acc.x + r2.x;
    float gf = slab[(size_t)(1 * 512 + u) * Nslab + n] + acc.y + r2.y;
    float gg = slab[(size_t)(2 * 512 + u) * Nslab + n] + acc.z + r2.z;
    float go = slab[(size_t)(3 * 512 + u) * Nslab + n] + acc.w + r2.w;

    float i_ = 1.f / (1.f + __expf(-gi));
    float f_ = 1.f / (1.f + __expf(-gf));
    float g_ = tanhf(gg);
    float o_ = 1.f / (1.f + __expf(-go));

    const int cidx = (d * 512 + u) * 64 + b;
    float cn = f_ * cst[cidx] + i_ * g_;
    float hn = o_ * tanhf(cn);
    float m  = mask[t * 64 + b];
    hn *= m; cn *= m;
    cst[cidx] = cn;

    float* ho = (float*)(h4_out + (size_t)d * 8192 + (size_t)(u >> 2) * 64 + b);
    ho[u & 3] = hn;

    if (outT){
      outT[(size_t)(d * 512 + u) * TBROWS + t * 64 + b] = hn;     // coalesced
    } else if (oHi){
      long o = (long)(t * 64 + b) * 1024 + d * 512 + u;
      unsigned short hb = f2bf_bits(hn);
      oHi[o] = hb;
      oLo[o] = f2bf_bits(hn - bf_bits2f(hb));
    } else {
      outF[(long)(t * 64 + b) * 1024 + d * 512 + u] = hn;
    }
  }
}

// ---------------------------------------------------------------- transposes [1024][TBROWS] -> [TBROWS][1024]
__global__ __launch_bounds__(256) void k_transpose_split(const float* __restrict__ src,
                                                         unsigned short* __restrict__ hi,
                                                         unsigned short* __restrict__ lo){
  __shared__ float tile[64][65];
  const int g0 = blockIdx.x * 64, n0 = blockIdx.y * 64;
  const int lane = threadIdx.x & 63, rg = threadIdx.x >> 6;
  #pragma unroll
  for (int i = 0; i < 16; i++){
    int row = rg * 16 + i;
    tile[row][lane] = src[(long)(g0 + row) * TBROWS + n0 + lane];
  }
  __syncthreads();
  #pragma unroll
  for (int i = 0; i < 16; i++){
    int row = rg * 16 + i;
    float v = tile[lane][row];
    long o = (long)(n0 + row) * 1024 + g0 + lane;
    unsigned short hb = f2bf_bits(v);
    hi[o] = hb;
    lo[o] = f2bf_bits(v - bf_bits2f(hb));
  }
}

__global__ __launch_bounds__(256) void k_transpose_out(const float* __restrict__ src,
                                                       float* __restrict__ dst){
  __shared__ float tile[64][65];
  const int g0 = blockIdx.x * 64, n0 = blockIdx.y * 64;
  const int lane = threadIdx.x & 63, rg = threadIdx.x >> 6;
  #pragma unroll
  for (int i = 0; i < 16; i++){
    int row = rg * 16 + i;
    tile[row][lane] = src[(long)(g0 + row) * TBROWS + n0 + lane];
  }
  __syncthreads();
  #pragma unroll
  for (int i = 0; i < 16; i++){
    int row = rg * 16 + i;
    dst[(long)(n0 + row) * 1024 + g0 + lane] = tile[lane][row];
  }
}

// ---------------------------------------------------------------- host
extern "C" void kernel_launch(void* const* d_in, const int* in_sizes, int n_in,
                              void* d_out, int out_size, void* d_ws, size_t ws_size,
                              hipStream_t stream)
{
  (void)in_sizes; (void)n_in; (void)out_size;
  const float* x    = (const float*)d_in[0];
  const float* mask = (const float*)d_in[1];
  const float* wih[2][2] = {{(const float*)d_in[2],  (const float*)d_in[6]},
                            {(const float*)d_in[10], (const float*)d_in[14]}};
  const float* whh[2][2] = {{(const float*)d_in[3],  (const float*)d_in[7]},
                            {(const float*)d_in[11], (const float*)d_in[15]}};
  const float* bih[2][2] = {{(const float*)d_in[4],  (const float*)d_in[8]},
                            {(const float*)d_in[12], (const float*)d_in[16]}};
  const float* bhh[2][2] = {{(const float*)d_in[5],  (const float*)d_in[9]},
                            {(const float*)d_in[13], (const float*)d_in[17]}};

  char* wsb = (char*)d_ws;
  size_t off = 0;
  auto alloc = [&](size_t bytes)->char*{
    char* p = wsb + off; off += (bytes + 255) & ~(size_t)255; return p;
  };

  unsigned short* xhi  = (unsigned short*)alloc((size_t)TBROWS * NIN * 2);
  unsigned short* xlo  = (unsigned short*)alloc((size_t)TBROWS * NIN * 2);
  unsigned short* o0hi = (unsigned short*)alloc((size_t)TBROWS * 1024 * 2);
  unsigned short* o0lo = (unsigned short*)alloc((size_t)TBROWS * 1024 * 2);

  unsigned short* wsp[2][2][2];  // [layer][dir][hi/lo]
  for (int l = 0; l < 2; l++){
    size_t nel = (size_t)G4 * (l ? 1024 : 512);
    for (int dd = 0; dd < 2; dd++){
      wsp[l][dd][0] = (unsigned short*)alloc(nel * 2);
      wsp[l][dd][1] = (unsigned short*)alloc(nel * 2);
    }
  }
  float4* w4[2][2];              // packed Whh: [512 u][512 k] float4
  for (int l = 0; l < 2; l++)
    for (int dd = 0; dd < 2; dd++)
      w4[l][dd] = (float4*)alloc((size_t)512 * 512 * 16);

  float4* h4buf = (float4*)alloc((size_t)2 * 2 * 8192 * 16);  // [parity][dir][8192] float4
  float*  cbuf  = (float*)alloc((size_t)2 * 512 * 64 * 4);

  size_t fixed = off;
  size_t tbuf_bytes = (size_t)1024 * TBROWS * 4;
  auto slab_b = [](int C){ return ((size_t)G4 * C * 64 * 4 + 255) & ~(size_t)255; };

  int C = 64, use_tbuf = 1;
  while (C > 8 && fixed + tbuf_bytes + 256 + 2 * slab_b(C) > ws_size) C >>= 1;
  if (fixed + tbuf_bytes + 256 + 2 * slab_b(C) > ws_size){
    use_tbuf = 0; C = 64;
    while (C > 8 && fixed + 2 * slab_b(C) > ws_size) C >>= 1;
  }

  float* tbuf = use_tbuf ? (float*)alloc(tbuf_bytes) : nullptr;
  float* slabF = (float*)alloc(slab_b(C));
  float* slabB = (float*)alloc(slab_b(C));
  const int Nslab = C * 64;
  const int phases = T_STEPS / C;

  // ---- prepasses
  k_split<<<2048, 256, 0, stream>>>(x, xhi, xlo, (long)TBROWS * NIN / 4);
  for (int l = 0; l < 2; l++){
    long n4 = (long)G4 * (l ? 1024 : 512) / 4;
    for (int dd = 0; dd < 2; dd++){
      k_split<<<1024, 256, 0, stream>>>(wih[l][dd], wsp[l][dd][0], wsp[l][dd][1], n4);
      k_pack_w<<<1024, 256, 0, stream>>>(whh[l][dd], w4[l][dd]);
    }
  }

  for (int layer = 0; layer < 2; layer++){
    const unsigned short* Bh = layer ? o0hi : xhi;
    const unsigned short* Bl = layer ? o0lo : xlo;
    const int K = layer ? 1024 : 512;

    hipMemsetAsync(h4buf, 0, (size_t)2 * 2 * 8192 * 16, stream);
    hipMemsetAsync(cbuf, 0, (size_t)2 * 512 * 64 * 4, stream);

    for (int p = 0; p < phases; p++){
      const int tf0 = p * C;
      const int tb0 = T_STEPS - (p + 1) * C;
      dim3 gg(16, Nslab / 128, 2);
      k_gemm_x3<<<gg, 256, 0, stream>>>(
          wsp[layer][0][0], wsp[layer][0][1], wsp[layer][1][0], wsp[layer][1][1],
          Bh, Bl, slabF, slabB,
          bih[layer][0], bhh[layer][0], bih[layer][1], bhh[layer][1],
          K, Nslab, tf0 * 64, tb0 * 64);

      for (int s = p * C; s < (p + 1) * C; s++){
        float4* h4in  = h4buf + (size_t)(s & 1) * (2 * 8192);
        float4* h4out = h4buf + (size_t)((s + 1) & 1) * (2 * 8192);
        const int sl = s - p * C;
        float* oT = use_tbuf ? tbuf : nullptr;
        unsigned short* dh = (!use_tbuf && layer == 0) ? o0hi : nullptr;
        unsigned short* dl = (!use_tbuf && layer == 0) ? o0lo : nullptr;
        float* dfo = (!use_tbuf && layer == 1) ? (float*)d_out : nullptr;
        k_step2<<<256, 512, 0, stream>>>(
            w4[layer][0], w4[layer][1], slabF, slabB,
            h4in, h4out, cbuf, mask, oT, dh, dl, dfo,
            s, T_STEPS - 1 - s, sl, C - 1 - sl, Nslab);
      }
    }

    if (use_tbuf){
      dim3 tg(16, 512);
      if (layer == 0) k_transpose_split<<<tg, 256, 0, stream>>>(tbuf, o0hi, o0lo);
      else            k_transpose_out  <<<tg, 256, 0, stream>>>(tbuf, (float*)d_out);
    }
  }
}